// Round 1
// baseline (3491.692 us; speedup 1.0000x reference)
//
#include <hip/hip_runtime.h>
#include <math.h>

// B=4, N=4096, C=1024, KV=1024, H=4, Ch=Kh=256
// Restructured dataflow (exact algebra):
//   G1[b,h]  = emb1_h^T  @ emb_alld_h            [256,256], K=4096
//   Gd[b,h]  = embd1_h^T @ emb_all_h
//   S1 = scale * Wq[h] @ G1 @ Wkd0^T ; Sd = scale * Wqd[h] @ Gd @ Wk0^T
//   p = softmax(instnorm(S)) over last dim
//   Pt1 = p1 @ Wvd0 ; Ptd = pd1 @ Wv0
//   M1[b][o, h*256+k'] = sum_c Wout[o, c*4+h]  * Pt1[b,h][c,k']
//   Md[b][o, h*256+k'] = sum_c Woutd[o, c*4+h] * Ptd[b,h][c,k']
//   O1[b] = emb_alld[b] @ M1[b]^T ; Od1[b] = emb_all[b] @ Md[b]^T

#define BK 16

// Generic batched tiled GEMM:  C[g][i,j] = alpha * sum_k A_g(i,k)*B_g(j,k-ish)
// element addr: A + (g>>2)*a_g1 + (g&3)*a_g2 + i*a_si + k*a_sk   (same for B with j)
// C addr:       C + (g>>2)*c_g1 + (g&3)*c_g2 + i*c_si + j        (col stride 1)
template <int MT>
__global__ __launch_bounds__(256) void gemm_generic(
    const float* __restrict__ A, const float* __restrict__ B, float* __restrict__ C,
    int K,
    long long a_g1, long long a_g2, int a_si, int a_sk,
    long long b_g1, long long b_g2, int b_sj, int b_sk,
    long long c_g1, long long c_g2, int c_si,
    float alpha)
{
    constexpr int TSZ = MT * 16;
    constexpr int PIT = TSZ + 4;
    __shared__ float As[BK * PIT];
    __shared__ float Bs[BK * PIT];

    const int g = blockIdx.z;
    const float* Ab = A + (long long)(g >> 2) * a_g1 + (long long)(g & 3) * a_g2;
    const float* Bb = B + (long long)(g >> 2) * b_g1 + (long long)(g & 3) * b_g2;
    float*       Cb = C + (long long)(g >> 2) * c_g1 + (long long)(g & 3) * c_g2;

    const int i0 = blockIdx.x * TSZ;
    const int j0 = blockIdx.y * TSZ;
    const int t  = threadIdx.x;
    const int tx = t & 15;
    const int ty = t >> 4;

    float acc[MT][MT];
#pragma unroll
    for (int u = 0; u < MT; ++u)
#pragma unroll
        for (int v = 0; v < MT; ++v) acc[u][v] = 0.f;

    for (int k0 = 0; k0 < K; k0 += BK) {
        // ---- stage A tile: As[kk][i] ----
        if (a_sk == 1) {
#pragma unroll
            for (int r = 0; r < MT; ++r) {
                int idx = r * 256 + t;
                int kk = idx & 15, i = idx >> 4;
                As[kk * PIT + i] = Ab[(long long)(i0 + i) * a_si + (k0 + kk)];
            }
        } else {
#pragma unroll
            for (int r = 0; r < MT; ++r) {
                int idx = r * 256 + t;
                int i = idx & (TSZ - 1), kk = idx / TSZ;
                As[kk * PIT + i] = Ab[(long long)(i0 + i) * a_si + (long long)(k0 + kk) * a_sk];
            }
        }
        // ---- stage B tile: Bs[kk][j] ----
        if (b_sk == 1) {
#pragma unroll
            for (int r = 0; r < MT; ++r) {
                int idx = r * 256 + t;
                int kk = idx & 15, j = idx >> 4;
                Bs[kk * PIT + j] = Bb[(long long)(j0 + j) * b_sj + (k0 + kk)];
            }
        } else {
#pragma unroll
            for (int r = 0; r < MT; ++r) {
                int idx = r * 256 + t;
                int j = idx & (TSZ - 1), kk = idx / TSZ;
                Bs[kk * PIT + j] = Bb[(long long)(j0 + j) * b_sj + (long long)(k0 + kk) * b_sk];
            }
        }
        __syncthreads();

#pragma unroll
        for (int kk = 0; kk < BK; ++kk) {
            float a[MT], b[MT];
#pragma unroll
            for (int u = 0; u < MT; u += 4) {
                float4 t4 = *(const float4*)&As[kk * PIT + ty * MT + u];
                a[u] = t4.x; a[u + 1] = t4.y; a[u + 2] = t4.z; a[u + 3] = t4.w;
                float4 s4 = *(const float4*)&Bs[kk * PIT + tx * MT + u];
                b[u] = s4.x; b[u + 1] = s4.y; b[u + 2] = s4.z; b[u + 3] = s4.w;
            }
#pragma unroll
            for (int u = 0; u < MT; ++u)
#pragma unroll
                for (int v = 0; v < MT; ++v) acc[u][v] += a[u] * b[v];
        }
        __syncthreads();
    }

#pragma unroll
    for (int u = 0; u < MT; ++u) {
        long long row = i0 + ty * MT + u;
#pragma unroll
        for (int v = 0; v < MT; v += 4) {
            float4 o;
            o.x = acc[u][v + 0] * alpha;
            o.y = acc[u][v + 1] * alpha;
            o.z = acc[u][v + 2] * alpha;
            o.w = acc[u][v + 3] * alpha;
            *(float4*)&Cb[row * c_si + j0 + tx * MT + v] = o;
        }
    }
}

// per-(path,b,h) plane mean / rstd over 256x256
__global__ __launch_bounds__(256) void stats_kernel(const float* __restrict__ S, float* __restrict__ st) {
    int pg = blockIdx.x;  // 0..31
    const float* s = S + (long long)pg * 65536;
    float sum = 0.f, sq = 0.f;
    for (int i = threadIdx.x; i < 65536; i += 256) {
        float v = s[i];
        sum += v;
        sq += v * v;
    }
#pragma unroll
    for (int off = 32; off; off >>= 1) {
        sum += __shfl_down(sum, off);
        sq  += __shfl_down(sq,  off);
    }
    __shared__ float r1[4], r2[4];
    int w = threadIdx.x >> 6;
    if ((threadIdx.x & 63) == 0) { r1[w] = sum; r2[w] = sq; }
    __syncthreads();
    if (threadIdx.x == 0) {
        float ts = r1[0] + r1[1] + r1[2] + r1[3];
        float tq = r2[0] + r2[1] + r2[2] + r2[3];
        float mean = ts * (1.0f / 65536.0f);
        float var = tq * (1.0f / 65536.0f) - mean * mean;
        st[pg * 2 + 0] = mean;
        st[pg * 2 + 1] = rsqrtf(var + 1e-5f);
    }
}

// softmax over k (256) for each row c, applying instance-norm affine first; in-place
__global__ __launch_bounds__(256) void softmax_kernel(float* __restrict__ S, const float* __restrict__ st) {
    int pg = blockIdx.y;
    int c = blockIdx.x;
    float mean = st[pg * 2 + 0], rstd = st[pg * 2 + 1];
    float* row = S + (long long)pg * 65536 + c * 256;
    int t = threadIdx.x;
    float x = (row[t] - mean) * rstd;
    float m = x;
#pragma unroll
    for (int off = 32; off; off >>= 1) m = fmaxf(m, __shfl_down(m, off));
    __shared__ float r1[4], r2[4];
    int w = t >> 6;
    if ((t & 63) == 0) r1[w] = m;
    __syncthreads();
    m = fmaxf(fmaxf(r1[0], r1[1]), fmaxf(r1[2], r1[3]));
    float e = expf(x - m);
    float ssum = e;
#pragma unroll
    for (int off = 32; off; off >>= 1) ssum += __shfl_down(ssum, off);
    if ((t & 63) == 0) r2[w] = ssum;
    __syncthreads();
    ssum = r2[0] + r2[1] + r2[2] + r2[3];
    row[t] = e / ssum;
}

extern "C" void kernel_launch(void* const* d_in, const int* in_sizes, int n_in,
                              void* d_out, int out_size, void* d_ws, size_t ws_size,
                              hipStream_t stream) {
    const float* emb1     = (const float*)d_in[0];
    const float* emb_all  = (const float*)d_in[1];
    const float* embd1    = (const float*)d_in[2];
    const float* emb_alld = (const float*)d_in[3];
    const float* Wq    = (const float*)d_in[4];
    const float* Wqd   = (const float*)d_in[5];
    const float* Wk0   = (const float*)d_in[6];
    const float* Wv0   = (const float*)d_in[7];
    const float* Wkd0  = (const float*)d_in[8];
    const float* Wvd0  = (const float*)d_in[9];
    const float* Wout  = (const float*)d_in[10];
    const float* Woutd = (const float*)d_in[11];
    float* out = (float*)d_out;

    float* ws = (float*)d_ws;
    float* G  = ws;               // 2*16*65536 = 2,097,152
    float* T  = ws + 2097152;     // 2,097,152
    float* S  = ws + 4194304;     // 2,097,152 (softmax in place)
    float* P  = ws + 6291456;     // 2,097,152
    float* Mb = ws + 8388608;     // 2*4*1024*1024 = 8,388,608
    float* st = ws + 16777216;    // 64
    // total ws use: ~67.1 MB

    const long long EMB = 4194304;  // 4096*1024 per batch
    dim3 blk(256);
    const float scale = 1.0f / 32.0f;  // 1/sqrt(1024)

    // 1-2: Gram matrices G[p,b,h] = X1_h^T @ X2_h, K=4096
    gemm_generic<4><<<dim3(4, 4, 16), blk, 0, stream>>>(
        emb1, emb_alld, G, 4096,
        EMB, 256, 1, 1024,  EMB, 256, 1, 1024,  262144, 65536, 256, 1.0f);
    gemm_generic<4><<<dim3(4, 4, 16), blk, 0, stream>>>(
        embd1, emb_all, G + 1048576, 4096,
        EMB, 256, 1, 1024,  EMB, 256, 1, 1024,  262144, 65536, 256, 1.0f);

    // 3-4: T = Wq_h @ G
    gemm_generic<4><<<dim3(4, 4, 16), blk, 0, stream>>>(
        Wq, G, T, 256,
        0, 65536, 256, 1,  262144, 65536, 1, 256,  262144, 65536, 256, 1.0f);
    gemm_generic<4><<<dim3(4, 4, 16), blk, 0, stream>>>(
        Wqd, G + 1048576, T + 1048576, 256,
        0, 65536, 256, 1,  262144, 65536, 1, 256,  262144, 65536, 256, 1.0f);

    // 5-6: S = scale * T @ Wk'^T
    gemm_generic<4><<<dim3(4, 4, 16), blk, 0, stream>>>(
        T, Wkd0, S, 256,
        262144, 65536, 256, 1,  0, 0, 256, 1,  262144, 65536, 256, scale);
    gemm_generic<4><<<dim3(4, 4, 16), blk, 0, stream>>>(
        T + 1048576, Wk0, S + 1048576, 256,
        262144, 65536, 256, 1,  0, 0, 256, 1,  262144, 65536, 256, scale);

    // 7-8: instance-norm stats + softmax (in place on S)
    stats_kernel<<<32, blk, 0, stream>>>(S, st);
    softmax_kernel<<<dim3(256, 32), blk, 0, stream>>>(S, st);

    // 9-10: Pt = p @ Wv'
    gemm_generic<4><<<dim3(4, 4, 16), blk, 0, stream>>>(
        S, Wvd0, P, 256,
        262144, 65536, 256, 1,  0, 0, 1, 256,  262144, 65536, 256, 1.0f);
    gemm_generic<4><<<dim3(4, 4, 16), blk, 0, stream>>>(
        S + 1048576, Wv0, P + 1048576, 256,
        262144, 65536, 256, 1,  0, 0, 1, 256,  262144, 65536, 256, 1.0f);

    // 11-12: Mb[b][o, h*256+k'] = sum_c Wout[o, c*4+h] * Pt[b,h][c,k']
    gemm_generic<8><<<dim3(8, 2, 16), blk, 0, stream>>>(
        Wout, P, Mb, 256,
        0, 1, 1024, 4,  262144, 65536, 1, 256,  1048576, 256, 1024, 1.0f);
    gemm_generic<8><<<dim3(8, 2, 16), blk, 0, stream>>>(
        Woutd, P + 1048576, Mb + 4194304, 256,
        0, 1, 1024, 4,  262144, 65536, 1, 256,  1048576, 256, 1024, 1.0f);

    // 13-14: O[b] = X[b] @ Mb[b]^T   (M=4096, N=1024, K=1024, batch=4)
    gemm_generic<8><<<dim3(32, 8, 4), blk, 0, stream>>>(
        emb_alld, Mb, out, 1024,
        0, EMB, 1024, 1,  0, 1048576, 1024, 1,  0, EMB, 1024, 1.0f);
    gemm_generic<8><<<dim3(32, 8, 4), blk, 0, stream>>>(
        emb_all, Mb + 4194304, out + 16777216, 1024,
        0, EMB, 1024, 1,  0, 1048576, 1024, 1,  0, EMB, 1024, 1.0f);
}

// Round 2
// 948.259 us; speedup vs baseline: 3.6822x; 3.6822x over previous
//
#include <hip/hip_runtime.h>
#include <math.h>

// B=4, N=4096, C=1024, KV=1024, H=4, Ch=Kh=256
// Dataflow (exact algebra):
//   G[p,b,h]  = X1_h^T @ X2_h   [256,256], K=4096   (bf16 MFMA, split-K x4)
//   T = Wq_h @ G ; S = scale * T @ Wk'^T            (fp32 generic)
//   p = softmax(instnorm(S)); P = p @ Wv'           (fp32)
//   Mb[p,b][o, h*256+k'] = sum_c W*[o, c*4+h] * P[p,b,h][c,k']   (fp32)
//   O[p,b] = X[b] @ Mb[p,b]^T                       (bf16 MFMA)

#define BK16 16
#define PITCH 40   // bf16 elems per LDS row (80B: 16B-aligned b128 frags, good write banks)

typedef __bf16 bf16x4 __attribute__((ext_vector_type(4)));
typedef __bf16 bf16x8 __attribute__((ext_vector_type(8)));
typedef float f32x4 __attribute__((ext_vector_type(4)));

// ---------------- generic fp32 tiled GEMM (middle chain) ----------------
template <int MT>
__global__ __launch_bounds__(256) void gemm_generic(
    const float* __restrict__ A, const float* __restrict__ B, float* __restrict__ C,
    int K,
    long long a_g1, long long a_g2, int a_si, int a_sk,
    long long b_g1, long long b_g2, int b_sj, int b_sk,
    long long c_g1, long long c_g2, int c_si,
    float alpha)
{
    constexpr int TSZ = MT * 16;
    constexpr int PIT = TSZ + 4;
    __shared__ float As[BK16 * PIT];
    __shared__ float Bs[BK16 * PIT];

    const int g = blockIdx.z;
    const float* Ab = A + (long long)(g >> 2) * a_g1 + (long long)(g & 3) * a_g2;
    const float* Bb = B + (long long)(g >> 2) * b_g1 + (long long)(g & 3) * b_g2;
    float*       Cb = C + (long long)(g >> 2) * c_g1 + (long long)(g & 3) * c_g2;

    const int i0 = blockIdx.x * TSZ;
    const int j0 = blockIdx.y * TSZ;
    const int t  = threadIdx.x;
    const int tx = t & 15;
    const int ty = t >> 4;

    float acc[MT][MT];
#pragma unroll
    for (int u = 0; u < MT; ++u)
#pragma unroll
        for (int v = 0; v < MT; ++v) acc[u][v] = 0.f;

    for (int k0 = 0; k0 < K; k0 += BK16) {
        if (a_sk == 1) {
#pragma unroll
            for (int r = 0; r < MT; ++r) {
                int idx = r * 256 + t;
                int kk = idx & 15, i = idx >> 4;
                As[kk * PIT + i] = Ab[(long long)(i0 + i) * a_si + (k0 + kk)];
            }
        } else {
#pragma unroll
            for (int r = 0; r < MT; ++r) {
                int idx = r * 256 + t;
                int i = idx & (TSZ - 1), kk = idx / TSZ;
                As[kk * PIT + i] = Ab[(long long)(i0 + i) * a_si + (long long)(k0 + kk) * a_sk];
            }
        }
        if (b_sk == 1) {
#pragma unroll
            for (int r = 0; r < MT; ++r) {
                int idx = r * 256 + t;
                int kk = idx & 15, j = idx >> 4;
                Bs[kk * PIT + j] = Bb[(long long)(j0 + j) * b_sj + (k0 + kk)];
            }
        } else {
#pragma unroll
            for (int r = 0; r < MT; ++r) {
                int idx = r * 256 + t;
                int j = idx & (TSZ - 1), kk = idx / TSZ;
                Bs[kk * PIT + j] = Bb[(long long)(j0 + j) * b_sj + (long long)(k0 + kk) * b_sk];
            }
        }
        __syncthreads();

#pragma unroll
        for (int kk = 0; kk < BK16; ++kk) {
            float a[MT], b[MT];
#pragma unroll
            for (int u = 0; u < MT; u += 4) {
                float4 t4 = *(const float4*)&As[kk * PIT + ty * MT + u];
                a[u] = t4.x; a[u + 1] = t4.y; a[u + 2] = t4.z; a[u + 3] = t4.w;
                float4 s4 = *(const float4*)&Bs[kk * PIT + tx * MT + u];
                b[u] = s4.x; b[u + 1] = s4.y; b[u + 2] = s4.z; b[u + 3] = s4.w;
            }
#pragma unroll
            for (int u = 0; u < MT; ++u)
#pragma unroll
                for (int v = 0; v < MT; ++v) acc[u][v] += a[u] * b[v];
        }
        __syncthreads();
    }

#pragma unroll
    for (int u = 0; u < MT; ++u) {
        long long row = i0 + ty * MT + u;
#pragma unroll
        for (int v = 0; v < MT; v += 4) {
            float4 o;
            o.x = acc[u][v + 0] * alpha;
            o.y = acc[u][v + 1] * alpha;
            o.z = acc[u][v + 2] * alpha;
            o.w = acc[u][v + 3] * alpha;
            *(float4*)&Cb[row * c_si + j0 + tx * MT + v] = o;
        }
    }
}

// ---------------- bf16 MFMA Gram: G[z] = X1^T @ X2, split-K ----------------
// grid (4 tiles, 4 ksplit, 32 z), block 256
__global__ __launch_bounds__(256) void gram_mfma(
    const float* __restrict__ emb1, const float* __restrict__ emb_all,
    const float* __restrict__ embd1, const float* __restrict__ emb_alld,
    float* __restrict__ Gpart)
{
    __shared__ __bf16 As[128 * PITCH];
    __shared__ __bf16 Bs[128 * PITCH];

    const int z = blockIdx.z;              // 0..31
    const int path = z >> 4, bh = z & 15;
    const int b = bh >> 2, h = bh & 3;
    const float* X1 = (path == 0 ? emb1     : embd1)   + (long long)b * 4194304 + h * 256;
    const float* X2 = (path == 0 ? emb_alld : emb_all) + (long long)b * 4194304 + h * 256;

    const int i0 = (blockIdx.x >> 1) * 128;
    const int j0 = (blockIdx.x & 1) * 128;
    const int kb0 = blockIdx.y * 1024;

    const int t = threadIdx.x;
    const int q  = t & 7;          // n-group (n0 = 4q)
    const int i4 = t >> 3;         // 0..31 (i-group)
    const int lane = t & 63;
    const int wave = t >> 6;
    const int wr = (wave >> 1) * 64, wc = (wave & 1) * 64;
    const int fm = lane & 15, fg = lane >> 4;

    f32x4 acc[4][4];
#pragma unroll
    for (int u = 0; u < 4; ++u)
#pragma unroll
        for (int v = 0; v < 4; ++v) acc[u][v] = (f32x4){0.f, 0.f, 0.f, 0.f};

    for (int kb = kb0; kb < kb0 + 1024; kb += 32) {
        float4 va[4], vb[4];
        const float* pa = X1 + (long long)(kb + q * 4) * 1024 + i0 + i4 * 4;
        const float* pb = X2 + (long long)(kb + q * 4) * 1024 + j0 + i4 * 4;
#pragma unroll
        for (int r = 0; r < 4; ++r) {
            va[r] = *(const float4*)(pa + (long long)r * 1024);
            vb[r] = *(const float4*)(pb + (long long)r * 1024);
        }
        __syncthreads();
        // 4x4 register transpose -> LDS [i][n]
#pragma unroll
        for (int c = 0; c < 4; ++c) {
            bf16x4 wa, wb;
#pragma unroll
            for (int r = 0; r < 4; ++r) {
                wa[r] = (__bf16)(((const float*)&va[r])[c]);
                wb[r] = (__bf16)(((const float*)&vb[r])[c]);
            }
            *(bf16x4*)&As[(i4 * 4 + c) * PITCH + q * 4] = wa;
            *(bf16x4*)&Bs[(i4 * 4 + c) * PITCH + q * 4] = wb;
        }
        __syncthreads();

        bf16x8 af[4], bfv[4];
#pragma unroll
        for (int mt = 0; mt < 4; ++mt)
            af[mt] = *(const bf16x8*)&As[(wr + mt * 16 + fm) * PITCH + fg * 8];
#pragma unroll
        for (int nt = 0; nt < 4; ++nt)
            bfv[nt] = *(const bf16x8*)&Bs[(wc + nt * 16 + fm) * PITCH + fg * 8];
#pragma unroll
        for (int mt = 0; mt < 4; ++mt)
#pragma unroll
            for (int nt = 0; nt < 4; ++nt)
                acc[mt][nt] = __builtin_amdgcn_mfma_f32_16x16x32_bf16(af[mt], bfv[nt], acc[mt][nt], 0, 0, 0);
    }

    float* Gp = Gpart + ((long long)blockIdx.y * 32 + z) * 65536;
    const int col = lane & 15, rq = (lane >> 4) * 4;
#pragma unroll
    for (int mt = 0; mt < 4; ++mt)
#pragma unroll
        for (int nt = 0; nt < 4; ++nt)
#pragma unroll
            for (int r = 0; r < 4; ++r)
                Gp[(i0 + wr + mt * 16 + rq + r) * 256 + (j0 + wc + nt * 16 + col)] = acc[mt][nt][r];
}

__global__ __launch_bounds__(256) void reduce_g(const float* __restrict__ Gpart, float* __restrict__ G) {
    int idx4 = blockIdx.x * 256 + threadIdx.x;   // float4 index, < 524288
    float4 s = *(const float4*)&Gpart[(long long)idx4 * 4];
    float4 a = *(const float4*)&Gpart[2097152 + (long long)idx4 * 4];
    float4 c = *(const float4*)&Gpart[4194304 + (long long)idx4 * 4];
    float4 d = *(const float4*)&Gpart[6291456 + (long long)idx4 * 4];
    float4 o;
    o.x = s.x + a.x + c.x + d.x;
    o.y = s.y + a.y + c.y + d.y;
    o.z = s.z + a.z + c.z + d.z;
    o.w = s.w + a.w + c.w + d.w;
    *(float4*)&G[(long long)idx4 * 4] = o;
}

// ---------------- bf16 MFMA big output GEMM: O = X @ Mb^T ----------------
// grid (32 m-tiles, 8 o-tiles, 8 z), block 256
__global__ __launch_bounds__(256) void obig_mfma(
    const float* __restrict__ emb_all, const float* __restrict__ emb_alld,
    const float* __restrict__ Mb, float* __restrict__ out)
{
    __shared__ __bf16 As[128 * PITCH];
    __shared__ __bf16 Bs[128 * PITCH];

    const int z = blockIdx.z;            // 0..7
    const int path = z >> 2, b = z & 3;
    const float* X  = (path == 0 ? emb_alld : emb_all) + (long long)b * 4194304;
    const float* Bm = Mb + (long long)path * 4194304 + (long long)b * 1048576;
    float* Ob = out + (long long)path * 16777216 + (long long)b * 4194304;

    const int m0 = blockIdx.x * 128;
    const int o0 = blockIdx.y * 128;

    const int t = threadIdx.x;
    const int q  = t & 7;          // k-group (k0 = 4q)
    const int mm = t >> 3;         // 0..31
    const int lane = t & 63;
    const int wave = t >> 6;
    const int wr = (wave >> 1) * 64, wc = (wave & 1) * 64;
    const int fm = lane & 15, fg = lane >> 4;

    f32x4 acc[4][4];
#pragma unroll
    for (int u = 0; u < 4; ++u)
#pragma unroll
        for (int v = 0; v < 4; ++v) acc[u][v] = (f32x4){0.f, 0.f, 0.f, 0.f};

    for (int kb = 0; kb < 1024; kb += 32) {
        float4 va[4], vb[4];
#pragma unroll
        for (int it = 0; it < 4; ++it) {
            va[it] = *(const float4*)&X [(long long)(m0 + mm + 32 * it) * 1024 + kb + q * 4];
            vb[it] = *(const float4*)&Bm[(long long)(o0 + mm + 32 * it) * 1024 + kb + q * 4];
        }
        __syncthreads();
#pragma unroll
        for (int it = 0; it < 4; ++it) {
            bf16x4 wa, wb;
#pragma unroll
            for (int r = 0; r < 4; ++r) {
                wa[r] = (__bf16)(((const float*)&va[it])[r]);
                wb[r] = (__bf16)(((const float*)&vb[it])[r]);
            }
            *(bf16x4*)&As[(mm + 32 * it) * PITCH + q * 4] = wa;
            *(bf16x4*)&Bs[(mm + 32 * it) * PITCH + q * 4] = wb;
        }
        __syncthreads();

        bf16x8 af[4], bfv[4];
#pragma unroll
        for (int mt = 0; mt < 4; ++mt)
            af[mt] = *(const bf16x8*)&As[(wr + mt * 16 + fm) * PITCH + fg * 8];
#pragma unroll
        for (int nt = 0; nt < 4; ++nt)
            bfv[nt] = *(const bf16x8*)&Bs[(wc + nt * 16 + fm) * PITCH + fg * 8];
#pragma unroll
        for (int mt = 0; mt < 4; ++mt)
#pragma unroll
            for (int nt = 0; nt < 4; ++nt)
                acc[mt][nt] = __builtin_amdgcn_mfma_f32_16x16x32_bf16(af[mt], bfv[nt], acc[mt][nt], 0, 0, 0);
    }

    const int col = lane & 15, rq = (lane >> 4) * 4;
#pragma unroll
    for (int mt = 0; mt < 4; ++mt)
#pragma unroll
        for (int nt = 0; nt < 4; ++nt)
#pragma unroll
            for (int r = 0; r < 4; ++r)
                Ob[(long long)(m0 + wr + mt * 16 + rq + r) * 1024 + (o0 + wc + nt * 16 + col)] = acc[mt][nt][r];
}

// ---------------- stats + softmax ----------------
__global__ __launch_bounds__(256) void stats_kernel(const float* __restrict__ S, float* __restrict__ st) {
    int pg = blockIdx.x;
    const float* s = S + (long long)pg * 65536;
    float sum = 0.f, sq = 0.f;
    for (int i = threadIdx.x; i < 65536; i += 256) {
        float v = s[i];
        sum += v;
        sq += v * v;
    }
#pragma unroll
    for (int off = 32; off; off >>= 1) {
        sum += __shfl_down(sum, off);
        sq  += __shfl_down(sq,  off);
    }
    __shared__ float r1[4], r2[4];
    int w = threadIdx.x >> 6;
    if ((threadIdx.x & 63) == 0) { r1[w] = sum; r2[w] = sq; }
    __syncthreads();
    if (threadIdx.x == 0) {
        float ts = r1[0] + r1[1] + r1[2] + r1[3];
        float tq = r2[0] + r2[1] + r2[2] + r2[3];
        float mean = ts * (1.0f / 65536.0f);
        float var = tq * (1.0f / 65536.0f) - mean * mean;
        st[pg * 2 + 0] = mean;
        st[pg * 2 + 1] = rsqrtf(var + 1e-5f);
    }
}

__global__ __launch_bounds__(256) void softmax_kernel(float* __restrict__ S, const float* __restrict__ st) {
    int pg = blockIdx.y;
    int c = blockIdx.x;
    float mean = st[pg * 2 + 0], rstd = st[pg * 2 + 1];
    float* row = S + (long long)pg * 65536 + c * 256;
    int t = threadIdx.x;
    float x = (row[t] - mean) * rstd;
    float m = x;
#pragma unroll
    for (int off = 32; off; off >>= 1) m = fmaxf(m, __shfl_down(m, off));
    __shared__ float r1[4], r2[4];
    int w = t >> 6;
    if ((t & 63) == 0) r1[w] = m;
    __syncthreads();
    m = fmaxf(fmaxf(r1[0], r1[1]), fmaxf(r1[2], r1[3]));
    float e = expf(x - m);
    float ssum = e;
#pragma unroll
    for (int off = 32; off; off >>= 1) ssum += __shfl_down(ssum, off);
    if ((t & 63) == 0) r2[w] = ssum;
    __syncthreads();
    ssum = r2[0] + r2[1] + r2[2] + r2[3];
    row[t] = e / ssum;
}

extern "C" void kernel_launch(void* const* d_in, const int* in_sizes, int n_in,
                              void* d_out, int out_size, void* d_ws, size_t ws_size,
                              hipStream_t stream) {
    const float* emb1     = (const float*)d_in[0];
    const float* emb_all  = (const float*)d_in[1];
    const float* embd1    = (const float*)d_in[2];
    const float* emb_alld = (const float*)d_in[3];
    const float* Wq    = (const float*)d_in[4];
    const float* Wqd   = (const float*)d_in[5];
    const float* Wk0   = (const float*)d_in[6];
    const float* Wv0   = (const float*)d_in[7];
    const float* Wkd0  = (const float*)d_in[8];
    const float* Wvd0  = (const float*)d_in[9];
    const float* Wout  = (const float*)d_in[10];
    const float* Woutd = (const float*)d_in[11];
    float* out = (float*)d_out;

    float* ws = (float*)d_ws;
    float* Gpart = ws;                 // 4 * 2,097,152 (dead after reduce_g)
    float* Mb    = ws;                 // 8,388,608 (aliases Gpart; written later)
    float* G  = ws + 8388608;          // 2,097,152
    float* T  = ws + 10485760;         // 2,097,152
    float* S  = ws + 12582912;         // 2,097,152
    float* P  = ws + 14680064;         // 2,097,152
    float* st = ws + 16777216;         // 64
    // total ws: ~67.1 MB (same footprint as round 1)

    dim3 blk(256);
    const float scale = 1.0f / 32.0f;

    // 1: Gram matrices (bf16 MFMA, split-K x4) + reduce
    gram_mfma<<<dim3(4, 4, 32), blk, 0, stream>>>(emb1, emb_all, embd1, emb_alld, Gpart);
    reduce_g<<<2048, blk, 0, stream>>>(Gpart, G);

    // 2: T = Wq_h @ G
    gemm_generic<4><<<dim3(4, 4, 16), blk, 0, stream>>>(
        Wq, G, T, 256,
        0, 65536, 256, 1,  262144, 65536, 1, 256,  262144, 65536, 256, 1.0f);
    gemm_generic<4><<<dim3(4, 4, 16), blk, 0, stream>>>(
        Wqd, G + 1048576, T + 1048576, 256,
        0, 65536, 256, 1,  262144, 65536, 1, 256,  262144, 65536, 256, 1.0f);

    // 3: S = scale * T @ Wk'^T
    gemm_generic<4><<<dim3(4, 4, 16), blk, 0, stream>>>(
        T, Wkd0, S, 256,
        262144, 65536, 256, 1,  0, 0, 256, 1,  262144, 65536, 256, scale);
    gemm_generic<4><<<dim3(4, 4, 16), blk, 0, stream>>>(
        T + 1048576, Wk0, S + 1048576, 256,
        262144, 65536, 256, 1,  0, 0, 256, 1,  262144, 65536, 256, scale);

    // 4: instance-norm stats + softmax (in place on S)
    stats_kernel<<<32, blk, 0, stream>>>(S, st);
    softmax_kernel<<<dim3(256, 32), blk, 0, stream>>>(S, st);

    // 5: P = p @ Wv'
    gemm_generic<4><<<dim3(4, 4, 16), blk, 0, stream>>>(
        S, Wvd0, P, 256,
        262144, 65536, 256, 1,  0, 0, 1, 256,  262144, 65536, 256, 1.0f);
    gemm_generic<4><<<dim3(4, 4, 16), blk, 0, stream>>>(
        S + 1048576, Wv0, P + 1048576, 256,
        262144, 65536, 256, 1,  0, 0, 1, 256,  262144, 65536, 256, 1.0f);

    // 6: Mb[b][o, h*256+k'] = sum_c W*[o, c*4+h] * P[b,h][c,k']
    gemm_generic<8><<<dim3(8, 2, 16), blk, 0, stream>>>(
        Wout, P, Mb, 256,
        0, 1, 1024, 4,  262144, 65536, 1, 256,  1048576, 256, 1024, 1.0f);
    gemm_generic<8><<<dim3(8, 2, 16), blk, 0, stream>>>(
        Woutd, P + 1048576, Mb + 4194304, 256,
        0, 1, 1024, 4,  262144, 65536, 1, 256,  1048576, 256, 1024, 1.0f);

    // 7: O = X @ Mb^T  (bf16 MFMA, both paths+batches in one dispatch)
    obig_mfma<<<dim3(32, 8, 8), blk, 0, stream>>>(emb_all, emb_alld, Mb, out);
}

// Round 3
// 629.318 us; speedup vs baseline: 5.5484x; 1.5068x over previous
//
#include <hip/hip_runtime.h>
#include <math.h>

// B=4, N=4096, C=1024, KV=1024, H=4, Ch=Kh=256
// z = (path<<4) | (b<<2) | h  for 32-group stages.
// path0 (O1): Xm=emb_alld, Xn=emb1, Wq, Wkd0, Wvd0, Wout, obig X=emb_alld
// path1 (Od1): Xm=emb_all, Xn=embd1, Wqd, Wk0, Wv0, Woutd, obig X=emb_all
// Chain: GT = Xm^T@Xn (per z) -> T = Wq@ (GT as B) -> S = T@Wk^T (*1/32)
//        p = softmax(instnorm(S)) -> PT = WvT@p^T -> Mb = WoutR@PT^T -> O = X@Mb^T

#define PITCH 40

typedef __bf16 bf16x4 __attribute__((ext_vector_type(4)));
typedef __bf16 bf16x8 __attribute__((ext_vector_type(8)));
typedef float f32x4 __attribute__((ext_vector_type(4)));

__device__ inline void gl2lds16(const void* g, void* l) {
    __builtin_amdgcn_global_load_lds(
        (const __attribute__((address_space(1))) unsigned int*)g,
        (__attribute__((address_space(3))) unsigned int*)l, 16, 0, 0);
}

// ---------------- prep: X fp32 -> bf16 ----------------
__global__ __launch_bounds__(256) void prep_x(const float* __restrict__ emb_all,
                                              const float* __restrict__ emb_alld,
                                              __bf16* __restrict__ Xb) {
    const float* src = blockIdx.y ? emb_alld : emb_all;
    __bf16* dst = Xb + (long long)blockIdx.y * 16777216;
    long long i4 = (long long)blockIdx.x * 256 + threadIdx.x;
    float4 v = *(const float4*)&src[i4 * 4];
    bf16x4 o = {(__bf16)v.x, (__bf16)v.y, (__bf16)v.z, (__bf16)v.w};
    *(bf16x4*)&dst[i4 * 4] = o;
}

// ---------------- prep: weights -> bf16 (+transpose/gather) ----------------
__global__ __launch_bounds__(256) void prep_w(
    const float* __restrict__ Wq, const float* __restrict__ Wqd,
    const float* __restrict__ Wk0, const float* __restrict__ Wv0,
    const float* __restrict__ Wkd0, const float* __restrict__ Wvd0,
    const float* __restrict__ Wout, const float* __restrict__ Woutd,
    __bf16* __restrict__ Wq_bf, __bf16* __restrict__ Wk_bf,
    __bf16* __restrict__ WvT_bf, __bf16* __restrict__ WoutR_bf)
{
    int id = blockIdx.x * 256 + threadIdx.x;
    if (id < 524288) {
        Wq_bf[id] = (__bf16)(id < 262144 ? Wq[id] : Wqd[id - 262144]);
    } else if (id < 655360) {
        int j = id - 524288;
        Wk_bf[j] = (__bf16)(j < 65536 ? Wkd0[j] : Wk0[j - 65536]);
    } else if (id < 786432) {
        int j = id - 655360;
        int p = j >> 16, r = (j >> 8) & 255, c2 = j & 255;
        const float* s = p ? Wv0 : Wvd0;
        WvT_bf[j] = (__bf16)s[c2 * 256 + r];   // WvT[m][k'] = Wv'[k'][m]
    } else if (id < 2883584) {
        int j = id - 786432;
        int p = j >> 20; int rem = j & 1048575; int h = rem >> 18; int oc = rem & 262143;
        int o = oc >> 8, c = oc & 255;
        const float* s = p ? Woutd : Wout;
        WoutR_bf[j] = (__bf16)s[o * 1024 + c * 4 + h];
    }
}

// ---------------- gram: GT partials = Xm^T @ Xn (fp32 in, split-K x4) ----------------
__global__ __launch_bounds__(256) void gram_mfma(
    const float* __restrict__ emb1, const float* __restrict__ emb_all,
    const float* __restrict__ embd1, const float* __restrict__ emb_alld,
    float* __restrict__ Gpart)
{
    __shared__ __bf16 As[128 * PITCH];
    __shared__ __bf16 Bs[128 * PITCH];

    const int z = blockIdx.z;
    const int path = z >> 4, bh = z & 15;
    const int b = bh >> 2, h = bh & 3;
    // m-side = Xm (emb_alld / emb_all), n-side = Xn (emb1 / embd1) -> output is G^T
    const float* Xm = (path == 0 ? emb_alld : emb_all) + (long long)b * 4194304 + h * 256;
    const float* Xn = (path == 0 ? emb1     : embd1)   + (long long)b * 4194304 + h * 256;

    const int i0 = (blockIdx.x >> 1) * 128;
    const int j0 = (blockIdx.x & 1) * 128;
    const int kb0 = blockIdx.y * 1024;

    const int t = threadIdx.x;
    const int q  = t & 7;
    const int i4 = t >> 3;
    const int lane = t & 63;
    const int wave = t >> 6;
    const int wr = (wave >> 1) * 64, wc = (wave & 1) * 64;
    const int fm = lane & 15, fg = lane >> 4;

    f32x4 acc[4][4];
#pragma unroll
    for (int u = 0; u < 4; ++u)
#pragma unroll
        for (int v = 0; v < 4; ++v) acc[u][v] = (f32x4){0.f, 0.f, 0.f, 0.f};

    for (int kb = kb0; kb < kb0 + 1024; kb += 32) {
        float4 va[4], vb[4];
        const float* pa = Xm + (long long)(kb + q * 4) * 1024 + i0 + i4 * 4;
        const float* pb = Xn + (long long)(kb + q * 4) * 1024 + j0 + i4 * 4;
#pragma unroll
        for (int r = 0; r < 4; ++r) {
            va[r] = *(const float4*)(pa + (long long)r * 1024);
            vb[r] = *(const float4*)(pb + (long long)r * 1024);
        }
        __syncthreads();
#pragma unroll
        for (int c = 0; c < 4; ++c) {
            bf16x4 wa, wb;
#pragma unroll
            for (int r = 0; r < 4; ++r) {
                wa[r] = (__bf16)(((const float*)&va[r])[c]);
                wb[r] = (__bf16)(((const float*)&vb[r])[c]);
            }
            *(bf16x4*)&As[(i4 * 4 + c) * PITCH + q * 4] = wa;
            *(bf16x4*)&Bs[(i4 * 4 + c) * PITCH + q * 4] = wb;
        }
        __syncthreads();

        bf16x8 af[4], bfv[4];
#pragma unroll
        for (int mt = 0; mt < 4; ++mt)
            af[mt] = *(const bf16x8*)&As[(wr + mt * 16 + fm) * PITCH + fg * 8];
#pragma unroll
        for (int nt = 0; nt < 4; ++nt)
            bfv[nt] = *(const bf16x8*)&Bs[(wc + nt * 16 + fm) * PITCH + fg * 8];
#pragma unroll
        for (int mt = 0; mt < 4; ++mt)
#pragma unroll
            for (int nt = 0; nt < 4; ++nt)
                acc[mt][nt] = __builtin_amdgcn_mfma_f32_16x16x32_bf16(af[mt], bfv[nt], acc[mt][nt], 0, 0, 0);
    }

    float* Gp = Gpart + ((long long)blockIdx.y * 32 + z) * 65536;
    const int col = lane & 15, rq = (lane >> 4) * 4;
#pragma unroll
    for (int mt = 0; mt < 4; ++mt)
#pragma unroll
        for (int nt = 0; nt < 4; ++nt)
#pragma unroll
            for (int r = 0; r < 4; ++r)
                Gp[(i0 + wr + mt * 16 + rq + r) * 256 + (j0 + wc + nt * 16 + col)] = acc[mt][nt][r];
}

__global__ __launch_bounds__(256) void reduce_g(const float* __restrict__ Gpart, __bf16* __restrict__ GT) {
    long long idx4 = (long long)blockIdx.x * 256 + threadIdx.x;   // < 524288
    float4 a = *(const float4*)&Gpart[idx4 * 4];
    float4 b = *(const float4*)&Gpart[2097152 + idx4 * 4];
    float4 c = *(const float4*)&Gpart[4194304 + idx4 * 4];
    float4 d = *(const float4*)&Gpart[6291456 + idx4 * 4];
    bf16x4 o;
    o[0] = (__bf16)(a.x + b.x + c.x + d.x);
    o[1] = (__bf16)(a.y + b.y + c.y + d.y);
    o[2] = (__bf16)(a.z + b.z + c.z + d.z);
    o[3] = (__bf16)(a.w + b.w + c.w + d.w);
    *(bf16x4*)&GT[idx4 * 4] = o;
}

// ---------------- generic NT MFMA: C[z] = alpha * A[z] @ B[z]^T ----------------
// A [M][K], B [N][K] both bf16 row-major pitch K. 64x64 tile/block.
// z offsets: (z>>4)*s1 + ((z>>2)&3)*s2 + (z&3)*s3
template <typename CT>
__global__ __launch_bounds__(256) void mfma_nt(
    const __bf16* __restrict__ A, const __bf16* __restrict__ B, CT* __restrict__ C,
    int mtiles, int K,
    long long a1, long long a2, long long a3,
    long long b1, long long b2, long long b3,
    long long c1, long long c2, long long c3,
    int cpitch, float alpha)
{
    __shared__ __bf16 As[64 * 32];
    __shared__ __bf16 Bs[64 * 32];
    const int z = blockIdx.y;
    const __bf16* Az = A + (long long)(z >> 4) * a1 + (long long)((z >> 2) & 3) * a2 + (long long)(z & 3) * a3;
    const __bf16* Bz = B + (long long)(z >> 4) * b1 + (long long)((z >> 2) & 3) * b2 + (long long)(z & 3) * b3;
    CT* Cz = C + (long long)(z >> 4) * c1 + (long long)((z >> 2) & 3) * c2 + (long long)(z & 3) * c3;

    const int tm = blockIdx.x % mtiles, tn = blockIdx.x / mtiles;
    const int t = threadIdx.x;
    const int lane = t & 63, wave = t >> 6;
    const int row = t >> 2, ch = t & 3;
    const int fm = lane & 15, fg = lane >> 4;

    const __bf16* ga = Az + (long long)(tm * 64 + row) * K + ch * 8;
    const __bf16* gb = Bz + (long long)(tn * 64 + row) * K + ch * 8;
    __bf16* la = &As[t * 8];
    __bf16* lb = &Bs[t * 8];

    f32x4 acc[4];
#pragma unroll
    for (int u = 0; u < 4; ++u) acc[u] = (f32x4){0.f, 0.f, 0.f, 0.f};

    for (int kb = 0; kb < K; kb += 32) {
        __syncthreads();
        gl2lds16(ga + kb, la);
        gl2lds16(gb + kb, lb);
        __syncthreads();
        bf16x8 bv = *(const bf16x8*)&Bs[(wave * 16 + fm) * 32 + fg * 8];
#pragma unroll
        for (int mt = 0; mt < 4; ++mt) {
            bf16x8 av = *(const bf16x8*)&As[(mt * 16 + fm) * 32 + fg * 8];
            acc[mt] = __builtin_amdgcn_mfma_f32_16x16x32_bf16(av, bv, acc[mt], 0, 0, 0);
        }
    }

    const int colc = tn * 64 + wave * 16 + fm;
    const int rq = fg * 4;
#pragma unroll
    for (int mt = 0; mt < 4; ++mt)
#pragma unroll
        for (int r = 0; r < 4; ++r) {
            int rowc = tm * 64 + mt * 16 + rq + r;
            Cz[(long long)rowc * cpitch + colc] = (CT)(acc[mt][r] * alpha);
        }
}

// ---------------- obig: O = X @ Mb^T (bf16 in, m97-style 128x128) ----------------
__global__ __launch_bounds__(256) void obig_mfma(
    const __bf16* __restrict__ Xall, const __bf16* __restrict__ Mb, float* __restrict__ out)
{
    __shared__ __bf16 As[128 * 32];
    __shared__ __bf16 Bs[128 * 32];

    const int z = blockIdx.z;
    const int path = z >> 2, b = z & 3;
    // Xall = [emb_all | emb_alld]; path0 uses emb_alld
    const __bf16* X = Xall + (path == 0 ? 16777216LL : 0LL) + (long long)b * 4194304;
    const __bf16* Bm = Mb + (long long)path * 4194304 + (long long)b * 1048576;
    float* Ob = out + (long long)path * 16777216 + (long long)b * 4194304;

    const int m0 = blockIdx.x * 128;
    const int o0 = blockIdx.y * 128;

    const int t = threadIdx.x;
    const int lane = t & 63, wave = t >> 6;
    const int wr = (wave >> 1) * 64, wc = (wave & 1) * 64;
    const int fm = lane & 15, fg = lane >> 4;
    const int row = t >> 2, ch = t & 3;

    const __bf16* ga0 = X + (long long)(m0 + row) * 1024 + ch * 8;
    const __bf16* ga1 = X + (long long)(m0 + 64 + row) * 1024 + ch * 8;
    const __bf16* gb0 = Bm + (long long)(o0 + row) * 1024 + ch * 8;
    const __bf16* gb1 = Bm + (long long)(o0 + 64 + row) * 1024 + ch * 8;
    __bf16* la0 = &As[t * 8];
    __bf16* la1 = &As[2048 + t * 8];
    __bf16* lb0 = &Bs[t * 8];
    __bf16* lb1 = &Bs[2048 + t * 8];

    f32x4 acc[4][4];
#pragma unroll
    for (int u = 0; u < 4; ++u)
#pragma unroll
        for (int v = 0; v < 4; ++v) acc[u][v] = (f32x4){0.f, 0.f, 0.f, 0.f};

    for (int kb = 0; kb < 1024; kb += 32) {
        __syncthreads();
        gl2lds16(ga0 + kb, la0);
        gl2lds16(ga1 + kb, la1);
        gl2lds16(gb0 + kb, lb0);
        gl2lds16(gb1 + kb, lb1);
        __syncthreads();

        bf16x8 af[4], bv[4];
#pragma unroll
        for (int mt = 0; mt < 4; ++mt)
            af[mt] = *(const bf16x8*)&As[(wr + mt * 16 + fm) * 32 + fg * 8];
#pragma unroll
        for (int nt = 0; nt < 4; ++nt)
            bv[nt] = *(const bf16x8*)&Bs[(wc + nt * 16 + fm) * 32 + fg * 8];
#pragma unroll
        for (int mt = 0; mt < 4; ++mt)
#pragma unroll
            for (int nt = 0; nt < 4; ++nt)
                acc[mt][nt] = __builtin_amdgcn_mfma_f32_16x16x32_bf16(af[mt], bv[nt], acc[mt][nt], 0, 0, 0);
    }

    const int col = lane & 15, rq = (lane >> 4) * 4;
#pragma unroll
    for (int mt = 0; mt < 4; ++mt)
#pragma unroll
        for (int nt = 0; nt < 4; ++nt)
#pragma unroll
            for (int r = 0; r < 4; ++r)
                Ob[(long long)(m0 + wr + mt * 16 + rq + r) * 1024 + (o0 + wc + nt * 16 + col)] = acc[mt][nt][r];
}

// ---------------- stats + softmax ----------------
__global__ __launch_bounds__(256) void stats_kernel(const float* __restrict__ S, float* __restrict__ st) {
    int pg = blockIdx.x;
    const float* s = S + (long long)pg * 65536;
    float sum = 0.f, sq = 0.f;
    for (int i = threadIdx.x; i < 65536; i += 256) {
        float v = s[i];
        sum += v;
        sq += v * v;
    }
#pragma unroll
    for (int off = 32; off; off >>= 1) {
        sum += __shfl_down(sum, off);
        sq  += __shfl_down(sq,  off);
    }
    __shared__ float r1[4], r2[4];
    int w = threadIdx.x >> 6;
    if ((threadIdx.x & 63) == 0) { r1[w] = sum; r2[w] = sq; }
    __syncthreads();
    if (threadIdx.x == 0) {
        float ts = r1[0] + r1[1] + r1[2] + r1[3];
        float tq = r2[0] + r2[1] + r2[2] + r2[3];
        float mean = ts * (1.0f / 65536.0f);
        float var = tq * (1.0f / 65536.0f) - mean * mean;
        st[pg * 2 + 0] = mean;
        st[pg * 2 + 1] = rsqrtf(var + 1e-5f);
    }
}

__global__ __launch_bounds__(256) void softmax_kernel(const float* __restrict__ S,
                                                      const float* __restrict__ st,
                                                      __bf16* __restrict__ p_bf) {
    int pg = blockIdx.y;
    int c = blockIdx.x;
    float mean = st[pg * 2 + 0], rstd = st[pg * 2 + 1];
    const float* row = S + (long long)pg * 65536 + c * 256;
    int t = threadIdx.x;
    float x = (row[t] - mean) * rstd;
    float m = x;
#pragma unroll
    for (int off = 32; off; off >>= 1) m = fmaxf(m, __shfl_down(m, off));
    __shared__ float r1[4], r2[4];
    int w = t >> 6;
    if ((t & 63) == 0) r1[w] = m;
    __syncthreads();
    m = fmaxf(fmaxf(r1[0], r1[1]), fmaxf(r1[2], r1[3]));
    float e = expf(x - m);
    float ssum = e;
#pragma unroll
    for (int off = 32; off; off >>= 1) ssum += __shfl_down(ssum, off);
    if ((t & 63) == 0) r2[w] = ssum;
    __syncthreads();
    ssum = r2[0] + r2[1] + r2[2] + r2[3];
    p_bf[(long long)pg * 65536 + c * 256 + t] = (__bf16)(e / ssum);
}

extern "C" void kernel_launch(void* const* d_in, const int* in_sizes, int n_in,
                              void* d_out, int out_size, void* d_ws, size_t ws_size,
                              hipStream_t stream) {
    const float* emb1     = (const float*)d_in[0];
    const float* emb_all  = (const float*)d_in[1];
    const float* embd1    = (const float*)d_in[2];
    const float* emb_alld = (const float*)d_in[3];
    const float* Wq    = (const float*)d_in[4];
    const float* Wqd   = (const float*)d_in[5];
    const float* Wk0   = (const float*)d_in[6];
    const float* Wv0   = (const float*)d_in[7];
    const float* Wkd0  = (const float*)d_in[8];
    const float* Wvd0  = (const float*)d_in[9];
    const float* Wout  = (const float*)d_in[10];
    const float* Woutd = (const float*)d_in[11];
    float* out = (float*)d_out;

    float* ws = (float*)d_ws;
    float*  Gpart   = ws;                             // 8,388,608 fl (dead after reduce_g)
    __bf16* Mb_bf   = (__bf16*)ws;                    // 8,388,608 bf16 (aliases Gpart)
    __bf16* X_bf    = (__bf16*)(ws + 8388608);        // 33,554,432 bf16 [emb_all | emb_alld]
    __bf16* GT_bf   = (__bf16*)(ws + 25165824);       // 2,097,152 bf16
    __bf16* T_bf    = (__bf16*)(ws + 26214400);       // 2,097,152 bf16
    float*  S       = ws + 27262976;                  // 2,097,152 fp32
    __bf16* p_bf    = (__bf16*)(ws + 29360128);       // 2,097,152 bf16
    __bf16* PT_bf   = (__bf16*)(ws + 30408704);       // 2,097,152 bf16
    __bf16* Wq_bf   = (__bf16*)(ws + 31457280);       // 524,288 bf16
    __bf16* Wk_bf   = (__bf16*)(ws + 31719424);       // 131,072 bf16
    __bf16* WvT_bf  = (__bf16*)(ws + 31784960);       // 131,072 bf16
    __bf16* WoutR_bf= (__bf16*)(ws + 31850496);       // 2,097,152 bf16
    float*  st      = ws + 32899072;                  // 64 fl  -> total ~131.6 MB

    dim3 blk(256);

    // prep
    prep_x<<<dim3(16384, 2), blk, 0, stream>>>(emb_all, emb_alld, X_bf);
    prep_w<<<11264, blk, 0, stream>>>(Wq, Wqd, Wk0, Wv0, Wkd0, Wvd0, Wout, Woutd,
                                      Wq_bf, Wk_bf, WvT_bf, WoutR_bf);

    // GT = Xm^T @ Xn (split-K x4) + reduce->bf16
    gram_mfma<<<dim3(4, 4, 32), blk, 0, stream>>>(emb1, emb_all, embd1, emb_alld, Gpart);
    reduce_g<<<2048, blk, 0, stream>>>(Gpart, GT_bf);

    // T = Wq_h @ G   (A=Wq_bf, B=GT)
    mfma_nt<__bf16><<<dim3(16, 32), blk, 0, stream>>>(
        Wq_bf, GT_bf, T_bf, 4, 256,
        262144, 0, 65536,  1048576, 262144, 65536,  1048576, 262144, 65536, 256, 1.0f);
    // S = scale * T @ Wk'^T
    mfma_nt<float><<<dim3(16, 32), blk, 0, stream>>>(
        T_bf, Wk_bf, S, 4, 256,
        1048576, 262144, 65536,  65536, 0, 0,  1048576, 262144, 65536, 256, 0.03125f);

    stats_kernel<<<32, blk, 0, stream>>>(S, st);
    softmax_kernel<<<dim3(256, 32), blk, 0, stream>>>(S, st, p_bf);

    // PT = WvT @ p^T
    mfma_nt<__bf16><<<dim3(16, 32), blk, 0, stream>>>(
        WvT_bf, p_bf, PT_bf, 4, 256,
        65536, 0, 0,  1048576, 262144, 65536,  1048576, 262144, 65536, 256, 1.0f);
    // Mb = WoutR @ PT^T   (M=1024)
    mfma_nt<__bf16><<<dim3(64, 32), blk, 0, stream>>>(
        WoutR_bf, PT_bf, Mb_bf, 16, 256,
        1048576, 0, 262144,  1048576, 262144, 65536,  4194304, 1048576, 256, 1024, 1.0f);

    // O = X @ Mb^T
    obig_mfma<<<dim3(32, 8, 8), blk, 0, stream>>>(X_bf, Mb_bf, out);
}